// Round 10
// baseline (1067.540 us; speedup 1.0000x reference)
//
#include <hip/hip_runtime.h>
#include <math.h>

#define NP 4096          // points per batch
#define NB 2             // batches
#define KNN 41
#define KPAD 48          // padded K (48*4 = 192 = 3 blocks of 64 columns)
#define PPW 4            // points per workgroup
#define NBLK 3
#define NPTS_TOT (NB*NP) // 8192
#define HUP 132          // hu row stride in floats (128 + 4 pad; 16B-aligned rows)

// Folded-weight layout in d_ws (float offsets). All bases 64B-aligned.
#define WS_W1T 0         // [6][64]
#define WS_SH1 384       // [64]
#define WS_W2T 448       // [64][64]   (ci-major, transposed)
#define WS_SH2 4544      // [64]
#define WS_W3T 4608      // [64][128]
#define WS_SH3 12800     // [128]
#define WS_W4T 12928     // [128][256]
#define WS_SH4 45696     // [256]
#define WS_W5F 45952     // [256][512] (co-major, scaled)
#define WS_SH5 177024    // [256]
#define WS_IDX_BYTES (177280*4)  // idx (8192*41 ints) lives after the weights

// ---------------------------------------------------------------------------
// Prep: fold BN scale into weights, transposed [ci][co] for scalar reads.
// ---------------------------------------------------------------------------
__global__ __launch_bounds__(256) void prep_weights(
    const float* __restrict__ w1, const float* __restrict__ g1, const float* __restrict__ b1,
    const float* __restrict__ m1, const float* __restrict__ v1,
    const float* __restrict__ w2, const float* __restrict__ g2, const float* __restrict__ b2,
    const float* __restrict__ m2, const float* __restrict__ v2,
    const float* __restrict__ w3, const float* __restrict__ g3, const float* __restrict__ b3,
    const float* __restrict__ m3, const float* __restrict__ v3,
    const float* __restrict__ w4, const float* __restrict__ g4, const float* __restrict__ b4,
    const float* __restrict__ m4, const float* __restrict__ v4,
    const float* __restrict__ w5, const float* __restrict__ g5, const float* __restrict__ b5,
    const float* __restrict__ m5, const float* __restrict__ v5,
    float* __restrict__ wsf)
{
  const int wg = blockIdx.x;
  const int t  = threadIdx.x;
  if (wg == 0) {
    if (t < 64) {
      const float i1 = g1[t] / sqrtf(v1[t] + 1e-5f);
      wsf[WS_SH1 + t] = b1[t] - m1[t]*i1;
#pragma unroll
      for (int ci = 0; ci < 6; ++ci) wsf[WS_W1T + ci*64 + t] = w1[t*6 + ci] * i1;
      const float i2 = g2[t] / sqrtf(v2[t] + 1e-5f);
      wsf[WS_SH2 + t] = b2[t] - m2[t]*i2;
    }
    if (t < 128) {
      const float i3 = g3[t] / sqrtf(v3[t] + 1e-5f);
      wsf[WS_SH3 + t] = b3[t] - m3[t]*i3;
    }
    {
      const float i4 = g4[t] / sqrtf(v4[t] + 1e-5f);
      wsf[WS_SH4 + t] = b4[t] - m4[t]*i4;
      const float i5 = g5[t] / sqrtf(v5[t] + 1e-5f);
      wsf[WS_SH5 + t] = b5[t] - m5[t]*i5;
    }
  } else if (wg == 1) {          // W2T: 4096 elems
    for (int e = t; e < 4096; e += 256) {
      const int ci = e >> 6, co = e & 63;
      const float inv = g2[co] / sqrtf(v2[co] + 1e-5f);
      wsf[WS_W2T + e] = w2[co*64 + ci] * inv;
    }
  } else if (wg == 2) {          // W3T: 8192 elems
    for (int e = t; e < 8192; e += 256) {
      const int ci = e >> 7, co = e & 127;
      const float inv = g3[co] / sqrtf(v3[co] + 1e-5f);
      wsf[WS_W3T + e] = w3[co*64 + ci] * inv;
    }
  } else if (wg <= 4) {          // W4T: 32768 elems over 2 WGs
    const int base = (wg - 3) * 16384;
    for (int k = t; k < 16384; k += 256) {
      const int e = base + k;
      const int ci = e >> 8, co = e & 255;
      const float inv = g4[co] / sqrtf(v4[co] + 1e-5f);
      wsf[WS_W4T + e] = w4[co*128 + ci] * inv;
    }
  } else {                       // W5F: 131072 elems over 32 WGs (wg 5..36)
    const int base = (wg - 5) * 4096;
    for (int k = t; k < 4096; k += 256) {
      const int e = base + k;
      const int co = e >> 9, q = e & 511;
      const float inv = g5[co] / sqrtf(v5[co] + 1e-5f);
      wsf[WS_W5F + e] = w5[co*512 + q] * inv;
    }
  }
}

// ---------------------------------------------------------------------------
// Kernel B: exact KNN (stable top-41 of -||xi-xj||^2) + feat output + idx.
// 8 rows per 512-thread WG (one wave per row) -> 24 waves/CU at 48KB LDS.
// ---------------------------------------------------------------------------
__global__ __launch_bounds__(512) void knn_feat_kernel(
    const float* __restrict__ x,      // (2,3,4096)
    float* __restrict__ feat_out,     // (2,6,4096,41)
    int* __restrict__ idx_ws)         // (8192,41)
{
  __shared__ float xs0[NP];
  __shared__ float xs1[NP];
  __shared__ float xs2[NP];
  __shared__ int idxbuf[8][KNN];
  __shared__ int flagbuf[8];

  const int tid  = threadIdx.x;
  const int wave = tid >> 6;
  const int lane = tid & 63;
  const int row0 = blockIdx.x * 8;          // 4096 % 8 == 0 -> never straddles batch
  const int b    = row0 >> 12;
  const float* xb = x + b * 3 * NP;

  for (int t = tid; t < NP; t += 512) {
    xs0[t] = xb[t];
    xs1[t] = xb[NP + t];
    xs2[t] = xb[2*NP + t];
  }
  if (lane == 0) flagbuf[wave] = 0;
  __syncthreads();

  const int i = (row0 & (NP-1)) + wave;
  const float a0 = xs0[i], a1 = xs1[i], a2 = xs2[i];
  const float xxi = (a0*a0 + a1*a1) + a2*a2;

  float lv[12]; int lj[12];
#pragma unroll
  for (int u = 0; u < 12; ++u) { lv[u] = -__builtin_inff(); lj[u] = -1; }

  for (int t = 0; t < NP/64; ++t) {
    const int j = t*64 + lane;
    const float b0 = xs0[j], b1 = xs1[j], b2 = xs2[j];
    const float dot  = fmaf(a2, b2, fmaf(a1, b1, a0*b0)); // GEMM k-ascending FMA chain
    const float xxj  = (b0*b0 + b1*b1) + b2*b2;
    const float inner = -2.0f * dot;
    const float pd   = ((0.0f - xxj) - inner) - xxi;      // ((-xx_j) - inner) - xx_i
    float cv = pd; int cj = j;
#pragma unroll
    for (int u = 0; u < 12; ++u) {
      const bool gt = (cv > lv[u]);
      const float tv = gt ? lv[u] : cv;
      const int   tj = gt ? lj[u] : cj;
      lv[u] = gt ? cv : lv[u];
      lj[u] = gt ? cj : lj[u];
      cv = tv; cj = tj;
    }
  }

  int pops = 0;
  for (int m = 0; m < KNN; ++m) {
    float vv = lv[0]; int jj = lj[0];
#pragma unroll
    for (int s = 1; s < 64; s <<= 1) {
      const float ov = __shfl_xor(vv, s);
      const int   oj = __shfl_xor(jj, s);
      const bool take = (ov > vv) || ((ov == vv) && ((unsigned)oj < (unsigned)jj));
      vv = take ? ov : vv;
      jj = take ? oj : jj;
    }
    if (lane == 0) idxbuf[wave][m] = jj;
    if (lj[0] == jj) {
#pragma unroll
      for (int u = 0; u < 11; ++u) { lv[u] = lv[u+1]; lj[u] = lj[u+1]; }
      lv[11] = -__builtin_inff(); lj[11] = -1;
      ++pops;
      if (pops == 12 && m < KNN-1) flagbuf[wave] = 1;
    }
  }

  if (flagbuf[wave] != 0 && lane == 0) {   // exact fallback, ~never runs
    float fv[KNN]; int fj[KNN];
    for (int u = 0; u < KNN; ++u) { fv[u] = -__builtin_inff(); fj[u] = -1; }
    for (int j = 0; j < NP; ++j) {
      const float b0 = xs0[j], b1 = xs1[j], b2 = xs2[j];
      const float dot = fmaf(a2, b2, fmaf(a1, b1, a0*b0));
      const float xxj = (b0*b0 + b1*b1) + b2*b2;
      const float pd  = ((0.0f - xxj) - (-2.0f*dot)) - xxi;
      if (pd > fv[KNN-1]) {
        int p = KNN-1;
        while (p > 0 && fv[p-1] < pd) { fv[p] = fv[p-1]; fj[p] = fj[p-1]; --p; }
        fv[p] = pd; fj[p] = j;
      }
    }
    for (int m = 0; m < KNN; ++m) idxbuf[wave][m] = fj[m];
  }

  if (lane < KNN) {
    const int j = idxbuf[wave][lane];
    idx_ws[(row0 + wave) * KNN + lane] = j;
    const int fo = b * 6 * NP * KNN;
    feat_out[fo + (0*NP + i)*KNN + lane] = xs0[j];
    feat_out[fo + (1*NP + i)*KNN + lane] = xs1[j];
    feat_out[fo + (2*NP + i)*KNN + lane] = xs2[j];
    feat_out[fo + (3*NP + i)*KNN + lane] = xs0[i];
    feat_out[fo + (4*NP + i)*KNN + lane] = xs1[i];
    feat_out[fo + (5*NP + i)*KNN + lane] = xs2[i];
  }
}

// ---------------------------------------------------------------------------
// 16-lane group max -> xbuf slot (float bits, values >= 0, init 0).
// No pad masking needed: pad columns duplicate the k=0 (self) column exactly.
// ---------------------------------------------------------------------------
__device__ __forceinline__ void kmax16(float y, int l, int* slot) {
  float r = y;
  r = fmaxf(r, __shfl_down(r, 8, 16));
  r = fmaxf(r, __shfl_down(r, 4, 16));
  r = fmaxf(r, __shfl_down(r, 2, 16));
  r = fmaxf(r, __shfl_down(r, 1, 16));
  if ((l & 15) == 0) atomicMax(slot, __float_as_int(r));
}

// ---------------------------------------------------------------------------
// Kernel C: fused conv chain S1..S4 (+ per-point max over K) + S5.
// 1024 threads = 16 waves; couts split 16-way -> 2 WGs/CU = 32 waves/CU
// (8/SIMD). feat loaded per-thread from global (x is L1/L2-resident).
// Activations transposed in LDS: hu[col][ci] (stride 132) -> ds_read_b128.
// Weights: BN-folded [ci][co] in ws, wave-uniform s_load.
// Union: h1 = hu[l][0:64], h2 = hu[l][64:128], h3 = hu[l][0:128] (mid-barrier).
// ---------------------------------------------------------------------------
__global__ __launch_bounds__(1024, 8) void fused_conv_kernel(
    const float* __restrict__ x,
    const int* __restrict__ idx_ws,
    const float* __restrict__ wsf,
    float* __restrict__ out)          // (2,256,4096)
{
  __shared__ float hu[64][HUP];       // 33.8 KB
  __shared__ int   xbuf[PPW][512];    // 8 KB; float bits, cat order [x1|x2|x3|x4]

  const int tid = threadIdx.x;
  const int w   = __builtin_amdgcn_readfirstlane(tid >> 6);  // 0..15
  const int l   = tid & 63;
  const int pt0 = blockIdx.x * PPW;

  for (int t = tid; t < PPW*512; t += 1024) ((int*)xbuf)[t] = 0;

  for (int blk = 0; blk < NBLK; ++blk) {
    const int s  = blk*64 + l;
    const int lp = s / KPAD;            // point slot 0..3 (16-lane groups never straddle)
    const int kk = s - lp*KPAD;         // k slot 0..47
    const int pt = pt0 + lp;
    const int bb = pt >> 12;
    const int n  = pt & (NP-1);

    // ---- per-thread feat loads (global; issued before the barrier) ----
    // pads (kk>=KNN) use j=n=self, duplicating the k=0 column (idx[0]==self).
    const int j = (kk < KNN) ? idx_ws[pt*KNN + kk] : n;
    const float f0 = x[(bb*3+0)*NP + j];
    const float f1 = x[(bb*3+1)*NP + j];
    const float f2 = x[(bb*3+2)*NP + j];
    const float f3 = x[(bb*3+0)*NP + n];
    const float f4 = x[(bb*3+1)*NP + n];
    const float f5 = x[(bb*3+2)*NP + n];
    __syncthreads();   // prev block's S4 hu reads complete before S1 writes

    // ---- S1: 6 -> 64 (4 couts/wave; writes hu[l][w*4 .. w*4+4)) ----
    {
      float acc[4];
#pragma unroll
      for (int cc = 0; cc < 4; ++cc) acc[cc] = 0.0f;
      const float f[6] = {f0, f1, f2, f3, f4, f5};
#pragma unroll
      for (int ci = 0; ci < 6; ++ci) {
        const float* wr = wsf + WS_W1T + ci*64 + w*4;
#pragma unroll
        for (int cc = 0; cc < 4; ++cc) acc[cc] = fmaf(wr[cc], f[ci], acc[cc]);
      }
      const float* sh = wsf + WS_SH1 + w*4;
      float y[4];
#pragma unroll
      for (int cc = 0; cc < 4; ++cc) y[cc] = fmaxf(acc[cc] + sh[cc], 0.0f);
      *(float4*)&hu[l][w*4] = make_float4(y[0], y[1], y[2], y[3]);
#pragma unroll
      for (int cc = 0; cc < 4; ++cc) kmax16(y[cc], l, &xbuf[lp][w*4 + cc]);
    }
    __syncthreads();

    // ---- S2: 64 -> 64 (reads hu[l][0:64] b128, writes hu[l][64+w*4..)) ----
    {
      float acc[4];
#pragma unroll
      for (int cc = 0; cc < 4; ++cc) acc[cc] = 0.0f;
#pragma unroll 2
      for (int q = 0; q < 16; ++q) {
        const float4 av = *(const float4*)&hu[l][q*4];
        const float* w0 = wsf + WS_W2T + (q*4+0)*64 + w*4;
        const float* w1 = wsf + WS_W2T + (q*4+1)*64 + w*4;
        const float* w2r = wsf + WS_W2T + (q*4+2)*64 + w*4;
        const float* w3r = wsf + WS_W2T + (q*4+3)*64 + w*4;
#pragma unroll
        for (int cc = 0; cc < 4; ++cc) acc[cc] = fmaf(w0[cc], av.x, acc[cc]);
#pragma unroll
        for (int cc = 0; cc < 4; ++cc) acc[cc] = fmaf(w1[cc], av.y, acc[cc]);
#pragma unroll
        for (int cc = 0; cc < 4; ++cc) acc[cc] = fmaf(w2r[cc], av.z, acc[cc]);
#pragma unroll
        for (int cc = 0; cc < 4; ++cc) acc[cc] = fmaf(w3r[cc], av.w, acc[cc]);
      }
      const float* sh = wsf + WS_SH2 + w*4;
      float y[4];
#pragma unroll
      for (int cc = 0; cc < 4; ++cc) y[cc] = fmaxf(acc[cc] + sh[cc], 0.0f);
      *(float4*)&hu[l][64 + w*4] = make_float4(y[0], y[1], y[2], y[3]);
#pragma unroll
      for (int cc = 0; cc < 4; ++cc) kmax16(y[cc], l, &xbuf[lp][64 + w*4 + cc]);
    }
    __syncthreads();

    // ---- S3: 64 -> 128 (reads hu[l][64:128] into acc, BARRIER, writes hu[l][w*8..)) ----
    {
      float acc[8];
#pragma unroll
      for (int cc = 0; cc < 8; ++cc) acc[cc] = 0.0f;
#pragma unroll 2
      for (int q = 0; q < 16; ++q) {
        const float4 av = *(const float4*)&hu[l][64 + q*4];
        const float* w0 = wsf + WS_W3T + (q*4+0)*128 + w*8;
        const float* w1 = wsf + WS_W3T + (q*4+1)*128 + w*8;
        const float* w2r = wsf + WS_W3T + (q*4+2)*128 + w*8;
        const float* w3r = wsf + WS_W3T + (q*4+3)*128 + w*8;
#pragma unroll
        for (int cc = 0; cc < 8; ++cc) acc[cc] = fmaf(w0[cc], av.x, acc[cc]);
#pragma unroll
        for (int cc = 0; cc < 8; ++cc) acc[cc] = fmaf(w1[cc], av.y, acc[cc]);
#pragma unroll
        for (int cc = 0; cc < 8; ++cc) acc[cc] = fmaf(w2r[cc], av.z, acc[cc]);
#pragma unroll
        for (int cc = 0; cc < 8; ++cc) acc[cc] = fmaf(w3r[cc], av.w, acc[cc]);
      }
      __syncthreads();   // all h2 reads done before h3 overwrites [64:128]
      const float* sh = wsf + WS_SH3 + w*8;
      float y[8];
#pragma unroll
      for (int cc = 0; cc < 8; ++cc) y[cc] = fmaxf(acc[cc] + sh[cc], 0.0f);
      *(float4*)&hu[l][w*8]     = make_float4(y[0], y[1], y[2], y[3]);
      *(float4*)&hu[l][w*8 + 4] = make_float4(y[4], y[5], y[6], y[7]);
#pragma unroll
      for (int cc = 0; cc < 8; ++cc) kmax16(y[cc], l, &xbuf[lp][128 + w*8 + cc]);
    }
    __syncthreads();

    // ---- S4: 128 -> 256 (16 couts/wave, no store) ----
    {
      float acc[16];
#pragma unroll
      for (int cc = 0; cc < 16; ++cc) acc[cc] = 0.0f;
#pragma unroll 2
      for (int q = 0; q < 32; ++q) {
        const float4 av = *(const float4*)&hu[l][q*4];
        const float* w0 = wsf + WS_W4T + (q*4+0)*256 + w*16;
        const float* w1 = wsf + WS_W4T + (q*4+1)*256 + w*16;
        const float* w2r = wsf + WS_W4T + (q*4+2)*256 + w*16;
        const float* w3r = wsf + WS_W4T + (q*4+3)*256 + w*16;
#pragma unroll
        for (int cc = 0; cc < 16; ++cc) acc[cc] = fmaf(w0[cc], av.x, acc[cc]);
#pragma unroll
        for (int cc = 0; cc < 16; ++cc) acc[cc] = fmaf(w1[cc], av.y, acc[cc]);
#pragma unroll
        for (int cc = 0; cc < 16; ++cc) acc[cc] = fmaf(w2r[cc], av.z, acc[cc]);
#pragma unroll
        for (int cc = 0; cc < 16; ++cc) acc[cc] = fmaf(w3r[cc], av.w, acc[cc]);
      }
      const float* sh = wsf + WS_SH4 + w*16;
#pragma unroll
      for (int cc = 0; cc < 16; ++cc) {
        const float y = fmaxf(acc[cc] + sh[cc], 0.0f);
        kmax16(y, l, &xbuf[lp][256 + w*16 + cc]);
      }
    }
    // no trailing barrier: next iteration's top barrier (or the pre-S5 one) covers it
  }
  __syncthreads();

  // ---- S5: 512 -> 256 on cat = [x1|x2|x3|x4]; 1 point per thread ----
  {
    const int co = tid & 255;
    const int pr = tid >> 8;          // 0..3
    float a0 = 0.f;
    const float4* wr  = (const float4*)(wsf + WS_W5F + co*512);
    const float4* xb0 = (const float4*)&xbuf[pr][0];
#pragma unroll 4
    for (int q = 0; q < 128; ++q) {
      const float4 wv = wr[q];
      const float4 x0 = xb0[q];
      a0 = fmaf(wv.x, x0.x, a0); a0 = fmaf(wv.y, x0.y, a0);
      a0 = fmaf(wv.z, x0.z, a0); a0 = fmaf(wv.w, x0.w, a0);
    }
    const float sh5 = wsf[WS_SH5 + co];
    const int bb = pt0 >> 12;
    const int n0 = (pt0 & (NP-1)) + pr;
    out[(bb*256 + co)*NP + n0] = fmaxf(a0 + sh5, 0.0f);
  }
}

// ---------------------------------------------------------------------------
extern "C" void kernel_launch(void* const* d_in, const int* in_sizes, int n_in,
                              void* d_out, int out_size, void* d_ws, size_t ws_size,
                              hipStream_t stream) {
  (void)in_sizes; (void)n_in; (void)out_size; (void)ws_size;
  const float* x = (const float*)d_in[0];
  const float* W[5], *G[5], *Bb[5], *M[5], *V[5];
  for (int i = 0; i < 5; ++i) {
    W[i]  = (const float*)d_in[1 + 5*i + 0];
    G[i]  = (const float*)d_in[1 + 5*i + 1];
    Bb[i] = (const float*)d_in[1 + 5*i + 2];
    M[i]  = (const float*)d_in[1 + 5*i + 3];
    V[i]  = (const float*)d_in[1 + 5*i + 4];
  }
  float* out = (float*)d_out;                    // (2,256,4096)
  float* feat_out = out + NB*256*NP;             // (2,6,4096,41)
  float* wsf = (float*)d_ws;
  int* idx_ws = (int*)((char*)d_ws + WS_IDX_BYTES);

  prep_weights<<<37, 256, 0, stream>>>(
      W[0], G[0], Bb[0], M[0], V[0],
      W[1], G[1], Bb[1], M[1], V[1],
      W[2], G[2], Bb[2], M[2], V[2],
      W[3], G[3], Bb[3], M[3], V[3],
      W[4], G[4], Bb[4], M[4], V[4],
      wsf);

  knn_feat_kernel<<<NPTS_TOT/8, 512, 0, stream>>>(x, feat_out, idx_ws);

  fused_conv_kernel<<<NPTS_TOT/PPW, 1024, 0, stream>>>(x, idx_ws, wsf, out);
}

// Round 11
// 775.004 us; speedup vs baseline: 1.3775x; 1.3775x over previous
//
#include <hip/hip_runtime.h>
#include <math.h>

#define NP 4096          // points per batch
#define NB 2             // batches
#define KNN 41
#define KPAD 48          // padded K (48*4 = 192 = 3 blocks of 64 columns)
#define PPW 4            // points per workgroup
#define NBLK 3
#define NPTS_TOT (NB*NP) // 8192
#define HUP 132          // hu row stride in floats (128 + 4 pad; 16B-aligned rows)

// Folded-weight layout in d_ws (float offsets). All bases 64B-aligned.
#define WS_W1T 0         // [6][64]
#define WS_SH1 384       // [64]
#define WS_W2T 448       // [64][64]   (ci-major, transposed)
#define WS_SH2 4544      // [64]
#define WS_W3T 4608      // [64][128]
#define WS_SH3 12800     // [128]
#define WS_W4T 12928     // [128][256]
#define WS_SH4 45696     // [256]
#define WS_W5F 45952     // [256][512] (co-major, scaled)
#define WS_SH5 177024    // [256]
#define WS_IDX_BYTES (177280*4)  // idx (8192*41 ints) lives after the weights

// ---------------------------------------------------------------------------
// Prep: fold BN scale into weights, transposed [ci][co] for scalar reads.
// ---------------------------------------------------------------------------
__global__ __launch_bounds__(256) void prep_weights(
    const float* __restrict__ w1, const float* __restrict__ g1, const float* __restrict__ b1,
    const float* __restrict__ m1, const float* __restrict__ v1,
    const float* __restrict__ w2, const float* __restrict__ g2, const float* __restrict__ b2,
    const float* __restrict__ m2, const float* __restrict__ v2,
    const float* __restrict__ w3, const float* __restrict__ g3, const float* __restrict__ b3,
    const float* __restrict__ m3, const float* __restrict__ v3,
    const float* __restrict__ w4, const float* __restrict__ g4, const float* __restrict__ b4,
    const float* __restrict__ m4, const float* __restrict__ v4,
    const float* __restrict__ w5, const float* __restrict__ g5, const float* __restrict__ b5,
    const float* __restrict__ m5, const float* __restrict__ v5,
    float* __restrict__ wsf)
{
  const int wg = blockIdx.x;
  const int t  = threadIdx.x;
  if (wg == 0) {
    if (t < 64) {
      const float i1 = g1[t] / sqrtf(v1[t] + 1e-5f);
      wsf[WS_SH1 + t] = b1[t] - m1[t]*i1;
#pragma unroll
      for (int ci = 0; ci < 6; ++ci) wsf[WS_W1T + ci*64 + t] = w1[t*6 + ci] * i1;
      const float i2 = g2[t] / sqrtf(v2[t] + 1e-5f);
      wsf[WS_SH2 + t] = b2[t] - m2[t]*i2;
    }
    if (t < 128) {
      const float i3 = g3[t] / sqrtf(v3[t] + 1e-5f);
      wsf[WS_SH3 + t] = b3[t] - m3[t]*i3;
    }
    {
      const float i4 = g4[t] / sqrtf(v4[t] + 1e-5f);
      wsf[WS_SH4 + t] = b4[t] - m4[t]*i4;
      const float i5 = g5[t] / sqrtf(v5[t] + 1e-5f);
      wsf[WS_SH5 + t] = b5[t] - m5[t]*i5;
    }
  } else if (wg == 1) {          // W2T: 4096 elems
    for (int e = t; e < 4096; e += 256) {
      const int ci = e >> 6, co = e & 63;
      const float inv = g2[co] / sqrtf(v2[co] + 1e-5f);
      wsf[WS_W2T + e] = w2[co*64 + ci] * inv;
    }
  } else if (wg == 2) {          // W3T: 8192 elems
    for (int e = t; e < 8192; e += 256) {
      const int ci = e >> 7, co = e & 127;
      const float inv = g3[co] / sqrtf(v3[co] + 1e-5f);
      wsf[WS_W3T + e] = w3[co*64 + ci] * inv;
    }
  } else if (wg <= 4) {          // W4T: 32768 elems over 2 WGs
    const int base = (wg - 3) * 16384;
    for (int k = t; k < 16384; k += 256) {
      const int e = base + k;
      const int ci = e >> 8, co = e & 255;
      const float inv = g4[co] / sqrtf(v4[co] + 1e-5f);
      wsf[WS_W4T + e] = w4[co*128 + ci] * inv;
    }
  } else {                       // W5F: 131072 elems over 32 WGs (wg 5..36)
    const int base = (wg - 5) * 4096;
    for (int k = t; k < 4096; k += 256) {
      const int e = base + k;
      const int co = e >> 9, q = e & 511;
      const float inv = g5[co] / sqrtf(v5[co] + 1e-5f);
      wsf[WS_W5F + e] = w5[co*512 + q] * inv;
    }
  }
}

// ---------------------------------------------------------------------------
// Kernel B: exact KNN (stable top-41 of -||xi-xj||^2) + feat output + idx.
// 8 rows per 512-thread WG (one wave per row) -> 24 waves/CU at 48KB LDS.
// ---------------------------------------------------------------------------
__global__ __launch_bounds__(512) void knn_feat_kernel(
    const float* __restrict__ x,      // (2,3,4096)
    float* __restrict__ feat_out,     // (2,6,4096,41)
    int* __restrict__ idx_ws)         // (8192,41)
{
  __shared__ float xs0[NP];
  __shared__ float xs1[NP];
  __shared__ float xs2[NP];
  __shared__ int idxbuf[8][KNN];
  __shared__ int flagbuf[8];

  const int tid  = threadIdx.x;
  const int wave = tid >> 6;
  const int lane = tid & 63;
  const int row0 = blockIdx.x * 8;          // 4096 % 8 == 0 -> never straddles batch
  const int b    = row0 >> 12;
  const float* xb = x + b * 3 * NP;

  for (int t = tid; t < NP; t += 512) {
    xs0[t] = xb[t];
    xs1[t] = xb[NP + t];
    xs2[t] = xb[2*NP + t];
  }
  if (lane == 0) flagbuf[wave] = 0;
  __syncthreads();

  const int i = (row0 & (NP-1)) + wave;
  const float a0 = xs0[i], a1 = xs1[i], a2 = xs2[i];
  const float xxi = (a0*a0 + a1*a1) + a2*a2;

  float lv[12]; int lj[12];
#pragma unroll
  for (int u = 0; u < 12; ++u) { lv[u] = -__builtin_inff(); lj[u] = -1; }

  for (int t = 0; t < NP/64; ++t) {
    const int j = t*64 + lane;
    const float b0 = xs0[j], b1 = xs1[j], b2 = xs2[j];
    const float dot  = fmaf(a2, b2, fmaf(a1, b1, a0*b0)); // GEMM k-ascending FMA chain
    const float xxj  = (b0*b0 + b1*b1) + b2*b2;
    const float inner = -2.0f * dot;
    const float pd   = ((0.0f - xxj) - inner) - xxi;      // ((-xx_j) - inner) - xx_i
    float cv = pd; int cj = j;
#pragma unroll
    for (int u = 0; u < 12; ++u) {
      const bool gt = (cv > lv[u]);
      const float tv = gt ? lv[u] : cv;
      const int   tj = gt ? lj[u] : cj;
      lv[u] = gt ? cv : lv[u];
      lj[u] = gt ? cj : lj[u];
      cv = tv; cj = tj;
    }
  }

  int pops = 0;
  for (int m = 0; m < KNN; ++m) {
    float vv = lv[0]; int jj = lj[0];
#pragma unroll
    for (int s = 1; s < 64; s <<= 1) {
      const float ov = __shfl_xor(vv, s);
      const int   oj = __shfl_xor(jj, s);
      const bool take = (ov > vv) || ((ov == vv) && ((unsigned)oj < (unsigned)jj));
      vv = take ? ov : vv;
      jj = take ? oj : jj;
    }
    if (lane == 0) idxbuf[wave][m] = jj;
    if (lj[0] == jj) {
#pragma unroll
      for (int u = 0; u < 11; ++u) { lv[u] = lv[u+1]; lj[u] = lj[u+1]; }
      lv[11] = -__builtin_inff(); lj[11] = -1;
      ++pops;
      if (pops == 12 && m < KNN-1) flagbuf[wave] = 1;
    }
  }

  if (flagbuf[wave] != 0 && lane == 0) {   // exact fallback, ~never runs
    float fv[KNN]; int fj[KNN];
    for (int u = 0; u < KNN; ++u) { fv[u] = -__builtin_inff(); fj[u] = -1; }
    for (int j = 0; j < NP; ++j) {
      const float b0 = xs0[j], b1 = xs1[j], b2 = xs2[j];
      const float dot = fmaf(a2, b2, fmaf(a1, b1, a0*b0));
      const float xxj = (b0*b0 + b1*b1) + b2*b2;
      const float pd  = ((0.0f - xxj) - (-2.0f*dot)) - xxi;
      if (pd > fv[KNN-1]) {
        int p = KNN-1;
        while (p > 0 && fv[p-1] < pd) { fv[p] = fv[p-1]; fj[p] = fj[p-1]; --p; }
        fv[p] = pd; fj[p] = j;
      }
    }
    for (int m = 0; m < KNN; ++m) idxbuf[wave][m] = fj[m];
  }

  if (lane < KNN) {
    const int j = idxbuf[wave][lane];
    idx_ws[(row0 + wave) * KNN + lane] = j;
    const int fo = b * 6 * NP * KNN;
    feat_out[fo + (0*NP + i)*KNN + lane] = xs0[j];
    feat_out[fo + (1*NP + i)*KNN + lane] = xs1[j];
    feat_out[fo + (2*NP + i)*KNN + lane] = xs2[j];
    feat_out[fo + (3*NP + i)*KNN + lane] = xs0[i];
    feat_out[fo + (4*NP + i)*KNN + lane] = xs1[i];
    feat_out[fo + (5*NP + i)*KNN + lane] = xs2[i];
  }
}

// ---------------------------------------------------------------------------
// 16-lane group max -> xbuf slot (float bits, values >= 0, init 0).
// No pad masking needed: pad columns duplicate the k=0 (self) column exactly.
// ---------------------------------------------------------------------------
__device__ __forceinline__ void kmax16(float y, int l, int* slot) {
  float r = y;
  r = fmaxf(r, __shfl_down(r, 8, 16));
  r = fmaxf(r, __shfl_down(r, 4, 16));
  r = fmaxf(r, __shfl_down(r, 2, 16));
  r = fmaxf(r, __shfl_down(r, 1, 16));
  if ((l & 15) == 0) atomicMax(slot, __float_as_int(r));
}

// ---------------------------------------------------------------------------
// Kernel C: fused conv chain S1..S4 (+ per-point max over K) + S5.
// 512 threads = 8 waves (the measured-good config: VGPR~40, 3 WGs/CU,
// 24 waves/CU). Round-10 lesson: 16 waves @ launch_bounds(1024,8) starved
// the allocator (VGPR 24) and doubled per-column DS reads -> 975us. Reverted.
// feat loaded per-thread from global (x is L2-resident).
// Activations transposed in LDS: hu[col][ci] (stride 132) -> ds_read_b128.
// Weights: BN-folded [ci][co] in ws, wave-uniform s_load.
// Union: h1 = hu[l][0:64], h2 = hu[l][64:128], h3 = hu[l][0:128] (mid-barrier).
// ---------------------------------------------------------------------------
__global__ __launch_bounds__(512, 6) void fused_conv_kernel(
    const float* __restrict__ x,
    const int* __restrict__ idx_ws,
    const float* __restrict__ wsf,
    float* __restrict__ out)          // (2,256,4096)
{
  __shared__ float hu[64][HUP];       // 33.8 KB
  __shared__ int   xbuf[PPW][512];    // 8 KB; float bits, cat order [x1|x2|x3|x4]

  const int tid = threadIdx.x;
  const int w   = __builtin_amdgcn_readfirstlane(tid >> 6);  // 0..7
  const int l   = tid & 63;
  const int pt0 = blockIdx.x * PPW;

  for (int t = tid; t < PPW*512; t += 512) ((int*)xbuf)[t] = 0;

  for (int blk = 0; blk < NBLK; ++blk) {
    const int s  = blk*64 + l;
    const int lp = s / KPAD;            // point slot 0..3 (16-lane groups never straddle)
    const int kk = s - lp*KPAD;         // k slot 0..47
    const int pt = pt0 + lp;
    const int bb = pt >> 12;
    const int n  = pt & (NP-1);

    // ---- per-thread feat loads (global; issued before the barrier) ----
    // pads (kk>=KNN) use j=n=self, duplicating the k=0 column (idx[0]==self).
    const int j = (kk < KNN) ? idx_ws[pt*KNN + kk] : n;
    const float f0 = x[(bb*3+0)*NP + j];
    const float f1 = x[(bb*3+1)*NP + j];
    const float f2 = x[(bb*3+2)*NP + j];
    const float f3 = x[(bb*3+0)*NP + n];
    const float f4 = x[(bb*3+1)*NP + n];
    const float f5 = x[(bb*3+2)*NP + n];
    __syncthreads();   // prev block's S4 hu reads complete before S1 writes

    // ---- S1: 6 -> 64 (8 couts/wave; writes hu[l][w*8 .. w*8+8)) ----
    {
      float acc[8];
#pragma unroll
      for (int cc = 0; cc < 8; ++cc) acc[cc] = 0.0f;
      const float f[6] = {f0, f1, f2, f3, f4, f5};
#pragma unroll
      for (int ci = 0; ci < 6; ++ci) {
        const float* wr = wsf + WS_W1T + ci*64 + w*8;
#pragma unroll
        for (int cc = 0; cc < 8; ++cc) acc[cc] = fmaf(wr[cc], f[ci], acc[cc]);
      }
      const float* sh = wsf + WS_SH1 + w*8;
      float y[8];
#pragma unroll
      for (int cc = 0; cc < 8; ++cc) y[cc] = fmaxf(acc[cc] + sh[cc], 0.0f);
      *(float4*)&hu[l][w*8]     = make_float4(y[0], y[1], y[2], y[3]);
      *(float4*)&hu[l][w*8 + 4] = make_float4(y[4], y[5], y[6], y[7]);
#pragma unroll
      for (int cc = 0; cc < 8; ++cc) kmax16(y[cc], l, &xbuf[lp][w*8 + cc]);
    }
    __syncthreads();

    // ---- S2: 64 -> 64 (reads hu[l][0:64] b128, writes hu[l][64+w*8..)) ----
    {
      float acc[8];
#pragma unroll
      for (int cc = 0; cc < 8; ++cc) acc[cc] = 0.0f;
#pragma unroll 2
      for (int q = 0; q < 16; ++q) {
        const float4 av = *(const float4*)&hu[l][q*4];
        const float* w0 = wsf + WS_W2T + (q*4+0)*64 + w*8;
        const float* w1 = wsf + WS_W2T + (q*4+1)*64 + w*8;
        const float* w2r = wsf + WS_W2T + (q*4+2)*64 + w*8;
        const float* w3r = wsf + WS_W2T + (q*4+3)*64 + w*8;
#pragma unroll
        for (int cc = 0; cc < 8; ++cc) acc[cc] = fmaf(w0[cc], av.x, acc[cc]);
#pragma unroll
        for (int cc = 0; cc < 8; ++cc) acc[cc] = fmaf(w1[cc], av.y, acc[cc]);
#pragma unroll
        for (int cc = 0; cc < 8; ++cc) acc[cc] = fmaf(w2r[cc], av.z, acc[cc]);
#pragma unroll
        for (int cc = 0; cc < 8; ++cc) acc[cc] = fmaf(w3r[cc], av.w, acc[cc]);
      }
      const float* sh = wsf + WS_SH2 + w*8;
      float y[8];
#pragma unroll
      for (int cc = 0; cc < 8; ++cc) y[cc] = fmaxf(acc[cc] + sh[cc], 0.0f);
      *(float4*)&hu[l][64 + w*8]     = make_float4(y[0], y[1], y[2], y[3]);
      *(float4*)&hu[l][64 + w*8 + 4] = make_float4(y[4], y[5], y[6], y[7]);
#pragma unroll
      for (int cc = 0; cc < 8; ++cc) kmax16(y[cc], l, &xbuf[lp][64 + w*8 + cc]);
    }
    __syncthreads();

    // ---- S3: 64 -> 128 (reads hu[l][64:128] into acc, BARRIER, writes hu[l][w*16..)) ----
    {
      float acc[16];
#pragma unroll
      for (int cc = 0; cc < 16; ++cc) acc[cc] = 0.0f;
#pragma unroll 2
      for (int q = 0; q < 16; ++q) {
        const float4 av = *(const float4*)&hu[l][64 + q*4];
        const float* w0 = wsf + WS_W3T + (q*4+0)*128 + w*16;
        const float* w1 = wsf + WS_W3T + (q*4+1)*128 + w*16;
        const float* w2r = wsf + WS_W3T + (q*4+2)*128 + w*16;
        const float* w3r = wsf + WS_W3T + (q*4+3)*128 + w*16;
#pragma unroll
        for (int cc = 0; cc < 16; ++cc) acc[cc] = fmaf(w0[cc], av.x, acc[cc]);
#pragma unroll
        for (int cc = 0; cc < 16; ++cc) acc[cc] = fmaf(w1[cc], av.y, acc[cc]);
#pragma unroll
        for (int cc = 0; cc < 16; ++cc) acc[cc] = fmaf(w2r[cc], av.z, acc[cc]);
#pragma unroll
        for (int cc = 0; cc < 16; ++cc) acc[cc] = fmaf(w3r[cc], av.w, acc[cc]);
      }
      __syncthreads();   // all h2 reads done before h3 overwrites [64:128]
      const float* sh = wsf + WS_SH3 + w*16;
      float y[16];
#pragma unroll
      for (int cc = 0; cc < 16; ++cc) y[cc] = fmaxf(acc[cc] + sh[cc], 0.0f);
#pragma unroll
      for (int qq = 0; qq < 4; ++qq)
        *(float4*)&hu[l][w*16 + qq*4] = make_float4(y[qq*4], y[qq*4+1], y[qq*4+2], y[qq*4+3]);
#pragma unroll
      for (int cc = 0; cc < 16; ++cc) kmax16(y[cc], l, &xbuf[lp][128 + w*16 + cc]);
    }
    __syncthreads();

    // ---- S4: 128 -> 256 (32 couts/wave, no store) ----
    {
      float acc[32];
#pragma unroll
      for (int cc = 0; cc < 32; ++cc) acc[cc] = 0.0f;
#pragma unroll 2
      for (int q = 0; q < 32; ++q) {
        const float4 av = *(const float4*)&hu[l][q*4];
        const float* w0 = wsf + WS_W4T + (q*4+0)*256 + w*32;
        const float* w1 = wsf + WS_W4T + (q*4+1)*256 + w*32;
        const float* w2r = wsf + WS_W4T + (q*4+2)*256 + w*32;
        const float* w3r = wsf + WS_W4T + (q*4+3)*256 + w*32;
#pragma unroll
        for (int cc = 0; cc < 32; ++cc) acc[cc] = fmaf(w0[cc], av.x, acc[cc]);
#pragma unroll
        for (int cc = 0; cc < 32; ++cc) acc[cc] = fmaf(w1[cc], av.y, acc[cc]);
#pragma unroll
        for (int cc = 0; cc < 32; ++cc) acc[cc] = fmaf(w2r[cc], av.z, acc[cc]);
#pragma unroll
        for (int cc = 0; cc < 32; ++cc) acc[cc] = fmaf(w3r[cc], av.w, acc[cc]);
      }
      const float* sh = wsf + WS_SH4 + w*32;
#pragma unroll
      for (int cc = 0; cc < 32; ++cc) {
        const float y = fmaxf(acc[cc] + sh[cc], 0.0f);
        kmax16(y, l, &xbuf[lp][256 + w*32 + cc]);
      }
    }
    // no trailing barrier: next iteration's top barrier (or the pre-S5 one) covers it
  }
  __syncthreads();

  // ---- S5: 512 -> 256 on cat = [x1|x2|x3|x4]; 2 points per thread ----
  {
    const int co = tid & 255;
    const int pr = tid >> 8;          // 0 or 1 -> points {0,1} / {2,3}
    float a0 = 0.f, a1 = 0.f;
    const float4* wr  = (const float4*)(wsf + WS_W5F + co*512);
    const float4* xb0 = (const float4*)&xbuf[pr*2    ][0];
    const float4* xb1 = (const float4*)&xbuf[pr*2 + 1][0];
#pragma unroll 4
    for (int q = 0; q < 128; ++q) {
      const float4 wv = wr[q];
      const float4 x0 = xb0[q];
      const float4 x1 = xb1[q];
      a0 = fmaf(wv.x, x0.x, a0); a0 = fmaf(wv.y, x0.y, a0);
      a0 = fmaf(wv.z, x0.z, a0); a0 = fmaf(wv.w, x0.w, a0);
      a1 = fmaf(wv.x, x1.x, a1); a1 = fmaf(wv.y, x1.y, a1);
      a1 = fmaf(wv.z, x1.z, a1); a1 = fmaf(wv.w, x1.w, a1);
    }
    const float sh5 = wsf[WS_SH5 + co];
    float2 res;
    res.x = fmaxf(a0 + sh5, 0.0f);
    res.y = fmaxf(a1 + sh5, 0.0f);
    const int bb = pt0 >> 12;
    const int n0 = (pt0 & (NP-1)) + pr*2;
    *(float2*)&out[(bb*256 + co)*NP + n0] = res;
  }
}

// ---------------------------------------------------------------------------
extern "C" void kernel_launch(void* const* d_in, const int* in_sizes, int n_in,
                              void* d_out, int out_size, void* d_ws, size_t ws_size,
                              hipStream_t stream) {
  (void)in_sizes; (void)n_in; (void)out_size; (void)ws_size;
  const float* x = (const float*)d_in[0];
  const float* W[5], *G[5], *Bb[5], *M[5], *V[5];
  for (int i = 0; i < 5; ++i) {
    W[i]  = (const float*)d_in[1 + 5*i + 0];
    G[i]  = (const float*)d_in[1 + 5*i + 1];
    Bb[i] = (const float*)d_in[1 + 5*i + 2];
    M[i]  = (const float*)d_in[1 + 5*i + 3];
    V[i]  = (const float*)d_in[1 + 5*i + 4];
  }
  float* out = (float*)d_out;                    // (2,256,4096)
  float* feat_out = out + NB*256*NP;             // (2,6,4096,41)
  float* wsf = (float*)d_ws;
  int* idx_ws = (int*)((char*)d_ws + WS_IDX_BYTES);

  prep_weights<<<37, 256, 0, stream>>>(
      W[0], G[0], Bb[0], M[0], V[0],
      W[1], G[1], Bb[1], M[1], V[1],
      W[2], G[2], Bb[2], M[2], V[2],
      W[3], G[3], Bb[3], M[3], V[3],
      W[4], G[4], Bb[4], M[4], V[4],
      wsf);

  knn_feat_kernel<<<NPTS_TOT/8, 512, 0, stream>>>(x, feat_out, idx_ws);

  fused_conv_kernel<<<NPTS_TOT/PPW, 512, 0, stream>>>(x, idx_ws, wsf, out);
}